// Round 8
// baseline (381.760 us; speedup 1.0000x reference)
//
#include <hip/hip_runtime.h>
#include <hip/hip_bf16.h>

// Problem constants (reference: T=8192, H=1024, I=2816, E=8)
#define T_TOK 8192
#define H_DIM 1024
#define I_DIM 2816
#define E_EXP 8

#define BK 32
#define MAXT (T_TOK / 256 + E_EXP) // 40 worst-case BM=256 tiles
#define GU_COLS (I_DIM / 128)      // 22
#define DN_COLS (H_DIM / 128)      // 8

typedef __bf16 bf16x8 __attribute__((ext_vector_type(8)));
typedef float f32x4 __attribute__((ext_vector_type(4)));

// swizzled LDS byte offset, [rows][32 bf16] tile, row stride 64B.
// involution: 16B-chunk ^= (row>>1)&3  (max 2-way bank aliasing = free)
#define SWZ32(r, bc) (((r) * 64) + ((bc) ^ ((((r) >> 1) & 3) << 4)))

__device__ __forceinline__ void gload16(const void* g, void* l) {
  __builtin_amdgcn_global_load_lds((const __attribute__((address_space(1))) void*)g,
                                   (__attribute__((address_space(3))) void*)l, 16, 0, 0);
}

__device__ __forceinline__ bf16x8 cvt8(const float4& p0, const float4& p1) {
  bf16x8 v;
  v[0] = (__bf16)p0.x; v[1] = (__bf16)p0.y; v[2] = (__bf16)p0.z; v[3] = (__bf16)p0.w;
  v[4] = (__bf16)p1.x; v[5] = (__bf16)p1.y; v[6] = (__bf16)p1.z; v[7] = (__bf16)p1.w;
  return v;
}

// bijective XCD-chunk swizzle (m204)
__device__ __forceinline__ int xcd_swizzle(int id, int nwg) {
  const int q = nwg >> 3, r = nwg & 7;
  const int xcd = id & 7, j = id >> 3;
  return (xcd < r ? xcd * (q + 1) : r * (q + 1) + (xcd - r) * q) + j;
}

// ---------------- bucketing kernels ----------------
__global__ void k_count(const int* __restrict__ idx, int* __restrict__ counts) {
  int t = blockIdx.x * blockDim.x + threadIdx.x;
  if (t < T_TOK) atomicAdd(&counts[idx[t]], 1);
}

__global__ void k_tilesB(const int* __restrict__ counts, int* __restrict__ offsets,
                         int* __restrict__ tE, int* __restrict__ tB,
                         int* __restrict__ tEnd, int* __restrict__ nT) {
  if (threadIdx.x != 0 || blockIdx.x != 0) return;
  int off = 0, nt = 0;
  for (int e = 0; e < E_EXP; ++e) {
    offsets[e] = off;
    int c = counts[e];
    for (int b = 0; b < c; b += 256) { tE[nt] = e; tB[nt] = off + b; tEnd[nt] = off + c; ++nt; }
    off += c;
  }
  offsets[E_EXP] = off;
  *nT = nt;
}

__global__ void k_scatter(const int* __restrict__ idx, const int* __restrict__ offsets,
                          int* __restrict__ cursor, int* __restrict__ order) {
  int t = blockIdx.x * blockDim.x + threadIdx.x;
  if (t < T_TOK) {
    int e = idx[t];
    int p = offsets[e] + atomicAdd(&cursor[e], 1);
    order[p] = t;
  }
}

// ---------------- bf16 pre-conversion (3 weight tensors, one launch) ----------------
__global__ __launch_bounds__(256) void k_cvt3(const float* __restrict__ s0, const float* __restrict__ s1,
                                              const float* __restrict__ s2, __bf16* __restrict__ d0,
                                              __bf16* __restrict__ d1, __bf16* __restrict__ d2, int n8each) {
  int i = blockIdx.x * blockDim.x + threadIdx.x;
  int seg = i / n8each;
  int j = i - seg * n8each;
  if (seg >= 3) return;
  const float* s = seg == 0 ? s0 : (seg == 1 ? s1 : s2);
  __bf16* d = seg == 0 ? d0 : (seg == 1 ? d1 : d2);
  const float4 p0 = ((const float4*)s)[j * 2];
  const float4 p1 = ((const float4*)s)[j * 2 + 1];
  ((bf16x8*)d)[j] = cvt8(p0, p1);
}

// gather by order + convert x -> xp (bf16, permuted rows)
__global__ __launch_bounds__(128) void k_xperm(const float* __restrict__ x,
                                               const int* __restrict__ order,
                                               __bf16* __restrict__ xp) {
  const int row = blockIdx.x;
  const int tok = order[row];
  const float* s = x + (size_t)tok * H_DIM + threadIdx.x * 8;
  const float4 p0 = ((const float4*)s)[0];
  const float4 p1 = ((const float4*)s)[1];
  *(bf16x8*)(xp + (size_t)row * H_DIM + threadIdx.x * 8) = cvt8(p0, p1);
}

// =====================================================================
// pass 2: gate/up GEMM + silu*mul -> hp
// BM=256 x BN=128 dual-op, BK=32, depth-1 prefetch; 64KB dynamic LDS
// -> 2 blocks/CU co-resident (barrier drain masked by sibling block).
// =====================================================================
__global__ __launch_bounds__(512) void k_gateup8(
    const __bf16* __restrict__ xp, const __bf16* __restrict__ wg, const __bf16* __restrict__ wu,
    const int* __restrict__ tE, const int* __restrict__ tB,
    const int* __restrict__ tEnd, const int* __restrict__ nT, __bf16* __restrict__ hp) {
  const int nwg = *nT * GU_COLS;
  const int id = blockIdx.x;
  if (id >= nwg) return;
  const int wgid = xcd_swizzle(id, nwg);
  const int tile = wgid / GU_COLS;
  const int col = wgid - tile * GU_COLS;
  const int e = tE[tile];
  const int rowbase = tB[tile];
  const int rowEnd = tEnd[tile];
  const int nbase = col * 128;

  extern __shared__ __align__(16) unsigned char smem[];
  unsigned char* smA = smem;          // [2][16384]  256 rows x 64B
  unsigned char* smG = smem + 32768;  // [2][8192]   128 rows x 64B
  unsigned char* smU = smem + 49152;  // [2][8192]

  const int tid = threadIdx.x;
  const int lane = tid & 63;
  const int w = tid >> 6;            // 0..7
  const int wm = w & 3, wn = w >> 2; // 4 x 2 wave grid, wave tile 64x64

  // staging: row = tid>>2 (+128 for A's 2nd half), source chunk pre-swizzled
  const int srow = tid >> 2;                    // 0..127
  const int sch = (tid & 3) ^ ((tid >> 3) & 3); // chunk ^ ((row>>1)&3)
  const __bf16* aS0 = xp + (size_t)(rowbase + srow) * H_DIM + sch * 8;
  const __bf16* aS1 = xp + (size_t)(rowbase + 128 + srow) * H_DIM + sch * 8;
  const __bf16* gS = wg + ((size_t)e * I_DIM + nbase + srow) * H_DIM + sch * 8;
  const __bf16* uS = wu + ((size_t)e * I_DIM + nbase + srow) * H_DIM + sch * 8;
  const int ldst = tid * 16; // linear LDS dest

  f32x4 accg[4][4], accu[4][4];
#pragma unroll
  for (int m = 0; m < 4; ++m)
#pragma unroll
    for (int n = 0; n < 4; ++n)
#pragma unroll
      for (int j = 0; j < 4; ++j) { accg[m][n][j] = 0.f; accu[m][n][j] = 0.f; }

  auto STAGE = [&](int kt, int b) {
    const size_t kof = (size_t)kt * BK;
    gload16(aS0 + kof, smA + b * 16384 + ldst);
    gload16(aS1 + kof, smA + b * 16384 + 8192 + ldst);
    gload16(gS + kof, smG + b * 8192 + ldst);
    gload16(uS + kof, smU + b * 8192 + ldst);
  };

  const int nK = H_DIM / BK; // 32
  STAGE(0, 0);
  __syncthreads();

  int cur = 0;
  const int kc = (lane >> 4) * 16; // 16B K-chunk within 64B row
  for (int kt = 0; kt < nK; ++kt) {
    if (kt + 1 < nK) STAGE(kt + 1, cur ^ 1); // prefetch (hidden under MFMA)
    const unsigned char* A = smA + cur * 16384;
    const unsigned char* G = smG + cur * 8192;
    const unsigned char* U = smU + cur * 8192;
    bf16x8 a[4], bg[4], bu[4];
#pragma unroll
    for (int m = 0; m < 4; ++m)
      a[m] = *(const bf16x8*)(A + SWZ32(wm * 64 + m * 16 + (lane & 15), kc));
#pragma unroll
    for (int n = 0; n < 4; ++n) {
      const int off = SWZ32(wn * 64 + n * 16 + (lane & 15), kc);
      bg[n] = *(const bf16x8*)(G + off);
      bu[n] = *(const bf16x8*)(U + off);
    }
#pragma unroll
    for (int m = 0; m < 4; ++m)
#pragma unroll
      for (int n = 0; n < 4; ++n) {
        accg[m][n] = __builtin_amdgcn_mfma_f32_16x16x32_bf16(a[m], bg[n], accg[m][n], 0, 0, 0);
        accu[m][n] = __builtin_amdgcn_mfma_f32_16x16x32_bf16(a[m], bu[n], accu[m][n], 0, 0, 0);
      }
    __syncthreads(); // prefetch arrived + all reads of cur done
    cur ^= 1;
  }

  // epilogue: h = silu(g)*u -> hp (bf16, permuted row layout)
#pragma unroll
  for (int m = 0; m < 4; ++m) {
    const int row0 = wm * 64 + m * 16 + (lane >> 4) * 4;
#pragma unroll
    for (int j = 0; j < 4; ++j) {
      const int gr = rowbase + row0 + j;
      if (gr < rowEnd) {
        __bf16* dst = hp + (size_t)gr * I_DIM + nbase;
#pragma unroll
        for (int n = 0; n < 4; ++n) {
          const int c2 = wn * 64 + n * 16 + (lane & 15);
          const float g = accg[m][n][j];
          const float u = accu[m][n][j];
          dst[c2] = (__bf16)(g / (1.f + __expf(-g)) * u);
        }
      }
    }
  }
}

// =====================================================================
// pass 3: down GEMM, scatter rows to out
// BM=256 x BN=128, BK=32, depth-1 prefetch; 48KB static LDS
// -> 3 blocks/CU capacity, entire ~288-block grid co-resident.
// =====================================================================
__global__ __launch_bounds__(512) void k_down8(
    const __bf16* __restrict__ hp, const __bf16* __restrict__ wd,
    const int* __restrict__ order, const int* __restrict__ tE, const int* __restrict__ tB,
    const int* __restrict__ tEnd, const int* __restrict__ nT, float* __restrict__ out) {
  const int nwg = *nT * DN_COLS;
  const int id = blockIdx.x;
  if (id >= nwg) return;
  const int wgid = xcd_swizzle(id, nwg);
  const int tile = wgid >> 3;
  const int col = wgid & 7;
  const int e = tE[tile];
  const int rowbase = tB[tile];
  const int rowEnd = tEnd[tile];
  const int nbase = col * 128; // over H

  __shared__ __align__(16) unsigned char smA[2][16384]; // 256 rows x 64B
  __shared__ __align__(16) unsigned char smB[2][8192];  // 128 rows x 64B

  const int tid = threadIdx.x;
  const int lane = tid & 63;
  const int w = tid >> 6;
  const int wm = w & 3, wn = w >> 2; // 4 x 2 wave grid, wave tile 64x64

  const int srow = tid >> 2;
  const int sch = (tid & 3) ^ ((tid >> 3) & 3);
  const __bf16* aS0 = hp + (size_t)(rowbase + srow) * I_DIM + sch * 8;
  const __bf16* aS1 = hp + (size_t)(rowbase + 128 + srow) * I_DIM + sch * 8;
  const __bf16* bS = wd + ((size_t)e * H_DIM + nbase + srow) * I_DIM + sch * 8;
  const int ldst = tid * 16;

  f32x4 acc[4][4];
#pragma unroll
  for (int m = 0; m < 4; ++m)
#pragma unroll
    for (int n = 0; n < 4; ++n)
#pragma unroll
      for (int j = 0; j < 4; ++j) acc[m][n][j] = 0.f;

  auto STAGE = [&](int kt, int b) {
    const size_t kof = (size_t)kt * BK;
    gload16(aS0 + kof, &smA[b][0] + ldst);
    gload16(aS1 + kof, &smA[b][0] + 8192 + ldst);
    gload16(bS + kof, &smB[b][0] + ldst);
  };

  const int nK = I_DIM / BK; // 88
  STAGE(0, 0);
  __syncthreads();

  int cur = 0;
  const int kc = (lane >> 4) * 16;
  for (int kt = 0; kt < nK; ++kt) {
    if (kt + 1 < nK) STAGE(kt + 1, cur ^ 1);
    const unsigned char* A = &smA[cur][0];
    const unsigned char* B = &smB[cur][0];
    bf16x8 a[4], b[4];
#pragma unroll
    for (int m = 0; m < 4; ++m)
      a[m] = *(const bf16x8*)(A + SWZ32(wm * 64 + m * 16 + (lane & 15), kc));
#pragma unroll
    for (int n = 0; n < 4; ++n)
      b[n] = *(const bf16x8*)(B + SWZ32(wn * 64 + n * 16 + (lane & 15), kc));
#pragma unroll
    for (int m = 0; m < 4; ++m)
#pragma unroll
      for (int n = 0; n < 4; ++n)
        acc[m][n] = __builtin_amdgcn_mfma_f32_16x16x32_bf16(a[m], b[n], acc[m][n], 0, 0, 0);
    __syncthreads();
    cur ^= 1;
  }

  // epilogue: scatter rows to out[token]
#pragma unroll
  for (int m = 0; m < 4; ++m) {
    const int row0 = wm * 64 + m * 16 + (lane >> 4) * 4;
#pragma unroll
    for (int j = 0; j < 4; ++j) {
      const int gr = rowbase + row0 + j;
      if (gr < rowEnd) {
        const int tok = order[gr];
        float* dst = out + (size_t)tok * H_DIM + nbase;
#pragma unroll
        for (int n = 0; n < 4; ++n) {
          const int c2 = wn * 64 + n * 16 + (lane & 15);
          dst[c2] = acc[m][n][j];
        }
      }
    }
  }
}

// ---------------- launch ----------------
extern "C" void kernel_launch(void* const* d_in, const int* in_sizes, int n_in,
                              void* d_out, int out_size, void* d_ws, size_t ws_size,
                              hipStream_t stream) {
  const float* x = (const float*)d_in[0];
  const int* eidx = (const int*)d_in[1];
  const float* Wg = (const float*)d_in[2];
  const float* Wu = (const float*)d_in[3];
  const float* Wd = (const float*)d_in[4];
  float* out = (float*)d_out;

  char* ws = (char*)d_ws;
  size_t off = 0;
  auto alloc = [&](size_t bytes) -> void* {
    void* p = ws + off;
    off = (off + bytes + 255) & ~(size_t)255;
    return p;
  };
  const size_t TPAD = T_TOK + 256; // tile overreads stay within +256 rows
  __bf16* hp = (__bf16*)alloc(TPAD * I_DIM * sizeof(__bf16));
  int* order = (int*)alloc(T_TOK * sizeof(int));
  int* offsets = (int*)alloc((E_EXP + 1) * sizeof(int));
  int* tE = (int*)alloc(MAXT * sizeof(int));
  int* tB = (int*)alloc(MAXT * sizeof(int));
  int* tEnd = (int*)alloc(MAXT * sizeof(int));
  int* nT = (int*)alloc(sizeof(int));
  int* cc = (int*)alloc(2 * E_EXP * sizeof(int)); // counts | cursor
  int* counts = cc;
  int* cursor = cc + E_EXP;

  const size_t WSZ = (size_t)E_EXP * I_DIM * H_DIM; // elements per weight tensor
  __bf16* xp = (__bf16*)alloc(TPAD * H_DIM * sizeof(__bf16));
  __bf16* wg16 = (__bf16*)alloc(WSZ * sizeof(__bf16));
  __bf16* wu16 = (__bf16*)alloc(WSZ * sizeof(__bf16));
  __bf16* wd16 = (__bf16*)alloc(WSZ * sizeof(__bf16));

  // opt in to 64KB dynamic LDS for gateup (not a stream op; capture-safe)
  hipFuncSetAttribute((const void*)k_gateup8,
                      hipFuncAttributeMaxDynamicSharedMemorySize, 65536);

  hipMemsetAsync(cc, 0, 2 * E_EXP * sizeof(int), stream);
  k_count<<<T_TOK / 256, 256, 0, stream>>>(eidx, counts);
  k_tilesB<<<1, 1, 0, stream>>>(counts, offsets, tE, tB, tEnd, nT);
  k_scatter<<<T_TOK / 256, 256, 0, stream>>>(eidx, offsets, cursor, order);

  const int n8 = (int)(WSZ / 8);
  k_cvt3<<<(3 * n8 + 255) / 256, 256, 0, stream>>>(Wg, Wu, Wd, wg16, wu16, wd16, n8);
  k_xperm<<<T_TOK, 128, 0, stream>>>(x, order, xp);

  k_gateup8<<<GU_COLS * MAXT, 512, 65536, stream>>>(xp, wg16, wu16, tE, tB, tEnd, nT, hp);
  k_down8<<<DN_COLS * MAXT, 512, 0, stream>>>(hp, wd16, order, tE, tB, tEnd, nT, out);
}